// Round 13
// baseline (48.022 us; speedup 1.0000x reference)
//
#include <hip/hip_runtime.h>
#include <hip/hip_bf16.h>

#define IN_FEATS 128
#define HIDDEN 32

typedef short v8s __attribute__((ext_vector_type(8)));
typedef unsigned short u16x8 __attribute__((ext_vector_type(8)));
typedef float v4f __attribute__((ext_vector_type(4)));
typedef float v2f __attribute__((ext_vector_type(2)));

__device__ __forceinline__ short hw_f2bf(float x) {
    __hip_bfloat16 b = __float2bfloat16(x);
    return *reinterpret_cast<short*>(&b);
}
__device__ __forceinline__ float bf2f_raw(unsigned short b) {
    union { float f; unsigned int u; } v; v.u = ((unsigned int)b) << 16;
    return v.f;
}

// ---------------------------------------------------------------------------
// Kernel 1: P[n][0:64] = embed[n] @ [W1s|W1d].T, b1 folded into the Ps half.
// Split scheme (R12): A*B ~= Ahi*(Bhi+Blo) -- B exact to ~17 mantissa bits
// across two MFMAs, A single-rounded bf16 (1 cvt/elem, no alo).
// 2 MFMAs per K-step (32/sub-tile, was 48).
// Per-block LDS W-pack. Fragment slot g=(nb*4+ks)*64+lane holds B[k][u],
// u = nb*16+(lane&15), k = ks*32+((lane>>4)&3)*8+j; A uses the identical
// (group,j)->k map so any common k-permutation cancels in the MFMA K-sum.
// C/D (HW-verified): col = lane&15, row = (lane>>4)*4 + reg.
// embed loads are non-temporal (read-once stream; keep L2 for P).
// ---------------------------------------------------------------------------
__global__ __launch_bounds__(256, 4) void precompute_P_mfma(
    const float* __restrict__ embed,
    const float* __restrict__ W1,
    const float* __restrict__ b1,
    unsigned short* __restrict__ P,        // bf16 [n][64]
    int n_nodes)
{
    __shared__ unsigned short sBhi[8192];  // 16 KB
    __shared__ unsigned short sBlo[8192];  // 16 KB

    const int t    = threadIdx.x;
    const int lane = t & 63;
    const int wave = t >> 6;

    // ---- Phase 0: pack W fragments into LDS (once per block; W1 L2-hits) ----
#pragma unroll
    for (int g0 = 0; g0 < 1024; g0 += 256) {
        const int g   = g0 + t;
        const int gl  = g & 63;
        const int ks  = (g >> 6) & 3;
        const int nb  = g >> 8;
        const int u   = nb * 16 + (gl & 15);
        const int k0  = ks * 32 + ((gl >> 4) & 3) * 8;
        const float* wp = W1 + (u & 31) * (2 * IN_FEATS) + (u >> 5) * IN_FEATS + k0;
        const float4 x0 = *reinterpret_cast<const float4*>(wp);
        const float4 x1 = *reinterpret_cast<const float4*>(wp + 4);
        const float xs[8] = {x0.x, x0.y, x0.z, x0.w, x1.x, x1.y, x1.z, x1.w};
        v8s h, l;
#pragma unroll
        for (int j = 0; j < 8; ++j) {
            const short hb = hw_f2bf(xs[j]);
            h[j] = hb;
            l[j] = hw_f2bf(xs[j] - bf2f_raw((unsigned short)hb));
        }
        *reinterpret_cast<v8s*>(sBhi + g * 8) = h;
        *reinterpret_cast<v8s*>(sBlo + g * 8) = l;
    }
    __syncthreads();

    // ---- per-lane output-unit biases (b1 folded into Ps half) ----
    const float bias_nb0 = b1[lane & 15];
    const float bias_nb1 = b1[16 + (lane & 15)];

    // ---- Phase 1: 2 sub-tiles of 16 nodes per wave ----
    const int last = n_nodes - 1;
    const int grp  = lane >> 4;

#pragma unroll
    for (int sub = 0; sub < 2; ++sub) {
        const int node0 = blockIdx.x * 128 + wave * 32 + sub * 16;
        if (node0 >= n_nodes) break;
        const int row = min(node0 + (lane & 15), last);

        // A fragments: single bf16 rounding (1 cvt/elem), non-temporal loads
        v8s ahi[4];
#pragma unroll
        for (int ks = 0; ks < 4; ++ks) {
            const float* ap = embed + (size_t)row * IN_FEATS + ks * 32 + grp * 8;
            const v4f x0 = __builtin_nontemporal_load(
                reinterpret_cast<const v4f*>(ap));
            const v4f x1 = __builtin_nontemporal_load(
                reinterpret_cast<const v4f*>(ap) + 1);
            const float xs[8] = {x0[0], x0[1], x0[2], x0[3],
                                 x1[0], x1[1], x1[2], x1[3]};
            v8s h;
#pragma unroll
            for (int j = 0; j < 8; ++j)
                h[j] = hw_f2bf(xs[j]);
            ahi[ks] = h;
        }

#pragma unroll
        for (int nb = 0; nb < 4; ++nb) {
            v8s bhi[4], blo[4];
#pragma unroll
            for (int ks = 0; ks < 4; ++ks) {
                const int fi = ((nb * 4 + ks) * 64 + lane) * 8;
                bhi[ks] = *reinterpret_cast<const v8s*>(sBhi + fi);
                blo[ks] = *reinterpret_cast<const v8s*>(sBlo + fi);
            }
            v4f acc = {0.f, 0.f, 0.f, 0.f};
#pragma unroll
            for (int ks = 0; ks < 4; ++ks) {
                acc = __builtin_amdgcn_mfma_f32_16x16x32_bf16(ahi[ks], bhi[ks], acc, 0, 0, 0);
                acc = __builtin_amdgcn_mfma_f32_16x16x32_bf16(ahi[ks], blo[ks], acc, 0, 0, 0);
            }
            const float bias = (nb == 0) ? bias_nb0 : (nb == 1) ? bias_nb1 : 0.f;
            const int u = nb * 16 + (lane & 15);
#pragma unroll
            for (int r = 0; r < 4; ++r) {
                const int n = node0 + grp * 4 + r;
                if (n < n_nodes)
                    P[(size_t)n * 64 + u] = (unsigned short)hw_f2bf(acc[r] + bias);
            }
        }
    }
}

// ---------------------------------------------------------------------------
// Kernel 2: per-edge  logits = relu(Ps[s] + Pd[d]) @ W2.T + b2   (b1 in Ps)
// 4 lanes per edge, 4 edges per quad (e+64k). Index loads and output stores
// are non-temporal (streams); P gathers stay cacheable (L2/L3-resident).
// ---------------------------------------------------------------------------
__global__ __launch_bounds__(256) void edge_classify_bf16(
    const int* __restrict__ src,
    const int* __restrict__ dst,
    const unsigned short* __restrict__ P,   // bf16 [n][64]
    const float* __restrict__ W2,
    const float* __restrict__ b2,
    float* __restrict__ out,
    int n_edges)
{
    const int t   = threadIdx.x;
    const int q   = t & 3;                      // quad lane: units 8q..8q+7
    const int qid = t >> 2;                     // 0..63
    const int e0  = blockIdx.x * 256 + qid;
    if (e0 >= n_edges) return;

    int se[4], de[4];
#pragma unroll
    for (int k = 0; k < 4; ++k) {
        const int e  = e0 + k * 64;
        const int ec = (e < n_edges) ? e : e0;
        se[k] = __builtin_nontemporal_load(src + ec);
        de[k] = __builtin_nontemporal_load(dst + ec);
    }

    u16x8 ps[4], pd[4];
#pragma unroll
    for (int k = 0; k < 4; ++k) {
        ps[k] = *reinterpret_cast<const u16x8*>(P + (size_t)se[k] * 64 + q * 8);
        pd[k] = *reinterpret_cast<const u16x8*>(P + (size_t)de[k] * 64 + 32 + q * 8);
    }

    const float4 w0a = *reinterpret_cast<const float4*>(W2 + q * 8);
    const float4 w0b = *reinterpret_cast<const float4*>(W2 + q * 8 + 4);
    const float4 w1a = *reinterpret_cast<const float4*>(W2 + HIDDEN + q * 8);
    const float4 w1b = *reinterpret_cast<const float4*>(W2 + HIDDEN + q * 8 + 4);
    const float ww0[8] = {w0a.x, w0a.y, w0a.z, w0a.w, w0b.x, w0b.y, w0b.z, w0b.w};
    const float ww1[8] = {w1a.x, w1a.y, w1a.z, w1a.w, w1b.x, w1b.y, w1b.z, w1b.w};

    float l0[4] = {0.f, 0.f, 0.f, 0.f};
    float l1[4] = {0.f, 0.f, 0.f, 0.f};
#pragma unroll
    for (int k = 0; k < 4; ++k) {
#pragma unroll
        for (int j = 0; j < 8; ++j) {
            float h = bf2f_raw(ps[k][j]) + bf2f_raw(pd[k][j]);
            h = fmaxf(h, 0.f);
            l0[k] = fmaf(h, ww0[j], l0[k]);
            l1[k] = fmaf(h, ww1[j], l1[k]);
        }
    }
#pragma unroll
    for (int k = 0; k < 4; ++k) {
        l0[k] += __shfl_xor(l0[k], 1); l0[k] += __shfl_xor(l0[k], 2);
        l1[k] += __shfl_xor(l1[k], 1); l1[k] += __shfl_xor(l1[k], 2);
    }
    if (q == 0) {
        const float bias0 = b2[0], bias1 = b2[1];
#pragma unroll
        for (int k = 0; k < 4; ++k) {
            const int e = e0 + k * 64;
            if (e < n_edges) {
                v2f v;
                v[0] = l0[k] + bias0;
                v[1] = l1[k] + bias1;
                __builtin_nontemporal_store(
                    v, reinterpret_cast<v2f*>(out + (size_t)e * 2));
            }
        }
    }
}

// ---------------------------------------------------------------------------
// Fallback (only if workspace too small): direct per-edge computation.
// ---------------------------------------------------------------------------
__global__ __launch_bounds__(256) void edge_direct(
    const int* __restrict__ src, const int* __restrict__ dst,
    const float* __restrict__ embed,
    const float* __restrict__ W1, const float* __restrict__ b1,
    const float* __restrict__ W2, const float* __restrict__ b2,
    float* __restrict__ out, int n_edges)
{
    const int e = blockIdx.x * 256 + threadIdx.x;
    if (e >= n_edges) return;
    const int s = src[e], d = dst[e];
    const float* se = embed + (size_t)s * IN_FEATS;
    const float* de = embed + (size_t)d * IN_FEATS;

    float acc[HIDDEN];
#pragma unroll
    for (int hh = 0; hh < HIDDEN; ++hh) acc[hh] = b1[hh];

    for (int c = 0; c < 4; ++c) {
        float es[32], ed[32];
#pragma unroll
        for (int q = 0; q < 8; ++q) {
            const float4 v = *reinterpret_cast<const float4*>(se + c * 32 + q * 4);
            es[q*4+0] = v.x; es[q*4+1] = v.y; es[q*4+2] = v.z; es[q*4+3] = v.w;
            const float4 u = *reinterpret_cast<const float4*>(de + c * 32 + q * 4);
            ed[q*4+0] = u.x; ed[q*4+1] = u.y; ed[q*4+2] = u.z; ed[q*4+3] = u.w;
        }
#pragma unroll
        for (int hh = 0; hh < HIDDEN; ++hh) {
            float acch = acc[hh];
#pragma unroll
            for (int k = 0; k < 32; ++k) {
                acch = fmaf(es[k], W1[hh * 256 + c * 32 + k], acch);
                acch = fmaf(ed[k], W1[hh * 256 + 128 + c * 32 + k], acch);
            }
            acc[hh] = acch;
        }
    }

    float l0 = b2[0], l1 = b2[1];
#pragma unroll
    for (int hh = 0; hh < HIDDEN; ++hh) {
        const float hv = fmaxf(acc[hh], 0.f);
        l0 = fmaf(hv, W2[hh], l0);
        l1 = fmaf(hv, W2[HIDDEN + hh], l1);
    }
    *reinterpret_cast<float2*>(out + (size_t)e * 2) = make_float2(l0, l1);
}

extern "C" void kernel_launch(void* const* d_in, const int* in_sizes, int n_in,
                              void* d_out, int out_size, void* d_ws, size_t ws_size,
                              hipStream_t stream)
{
    const int*   src = (const int*)d_in[0];
    const int*   dst = (const int*)d_in[1];
    const float* emb = (const float*)d_in[2];
    const float* W1  = (const float*)d_in[3];
    const float* b1  = (const float*)d_in[4];
    const float* W2  = (const float*)d_in[5];
    const float* b2  = (const float*)d_in[6];
    float* out = (float*)d_out;

    const int n_edges = in_sizes[0];
    const int n_nodes = in_sizes[2] / IN_FEATS;

    const size_t p_bytes = (size_t)n_nodes * 64 * sizeof(unsigned short);

    if (ws_size >= p_bytes) {
        unsigned short* P = (unsigned short*)d_ws;
        const int nb_nodes = (n_nodes + 127) / 128;   // 128 nodes per block
        precompute_P_mfma<<<nb_nodes, 256, 0, stream>>>(emb, W1, b1, P, n_nodes);
        const int nb_edges = (n_edges + 255) / 256;   // 256 edges per block
        edge_classify_bf16<<<nb_edges, 256, 0, stream>>>(src, dst, P, W2, b2, out, n_edges);
    } else {
        const int nb_edges = (n_edges + 255) / 256;
        edge_direct<<<nb_edges, 256, 0, stream>>>(src, dst, emb, W1, b1, W2, b2, out, n_edges);
    }
}

// Round 14
// 39.494 us; speedup vs baseline: 1.2159x; 1.2159x over previous
//
#include <hip/hip_runtime.h>
#include <hip/hip_bf16.h>

#define IN_FEATS 128
#define HIDDEN 32

typedef short v8s __attribute__((ext_vector_type(8)));
typedef unsigned short u16x8 __attribute__((ext_vector_type(8)));
typedef float v4f __attribute__((ext_vector_type(4)));

__device__ __forceinline__ short hw_f2bf(float x) {
    __hip_bfloat16 b = __float2bfloat16(x);
    return *reinterpret_cast<short*>(&b);
}
__device__ __forceinline__ float bf2f_raw(unsigned short b) {
    union { float f; unsigned int u; } v; v.u = ((unsigned int)b) << 16;
    return v.f;
}

// ---------------------------------------------------------------------------
// Kernel 1: P[n][0:64] = embed[n] @ [W1s|W1d].T, b1 folded into the Ps half.
// Split scheme: A*B ~= Ahi*(Bhi+Blo) -- B exact to ~17 mantissa bits across
// two MFMAs, A single-rounded bf16. 2 MFMAs per K-step.
//
// u-mapping (R14): u = (lane&15)*4 + nb  -- so after the nb loop each lane
// holds 4 CONTIGUOUS units per output row; pack to ushort4 and each 16-lane
// group stores a full 128B row in one instruction (was 16 scalar 2B stores).
// Fragment slot g=(nb*4+ks)*64+lane holds B[k][u], k=ks*32+((lane>>4)&3)*8+j;
// A uses the identical (group,j)->k map so any common k-permutation cancels.
// C/D (HW-verified): col = lane&15, row = (lane>>4)*4 + reg.
// R13 lesson: NO non-temporal hints (nt bypassed L1; 7us regression).
// ---------------------------------------------------------------------------
__global__ __launch_bounds__(256, 4) void precompute_P_mfma(
    const float* __restrict__ embed,
    const float* __restrict__ W1,
    const float* __restrict__ b1,
    unsigned short* __restrict__ P,        // bf16 [n][64]
    int n_nodes)
{
    __shared__ unsigned short sBhi[8192];  // 16 KB
    __shared__ unsigned short sBlo[8192];  // 16 KB

    const int t    = threadIdx.x;
    const int lane = t & 63;
    const int wave = t >> 6;

    // ---- Phase 0: pack W fragments into LDS (once per block; W1 L2-hits) ----
#pragma unroll
    for (int g0 = 0; g0 < 1024; g0 += 256) {
        const int g   = g0 + t;
        const int gl  = g & 63;
        const int ks  = (g >> 6) & 3;
        const int nb  = g >> 8;
        const int u   = (gl & 15) * 4 + nb;          // R14 u-mapping
        const int k0  = ks * 32 + ((gl >> 4) & 3) * 8;
        const float* wp = W1 + (u & 31) * (2 * IN_FEATS) + (u >> 5) * IN_FEATS + k0;
        const float4 x0 = *reinterpret_cast<const float4*>(wp);
        const float4 x1 = *reinterpret_cast<const float4*>(wp + 4);
        const float xs[8] = {x0.x, x0.y, x0.z, x0.w, x1.x, x1.y, x1.z, x1.w};
        v8s h, l;
#pragma unroll
        for (int j = 0; j < 8; ++j) {
            const short hb = hw_f2bf(xs[j]);
            h[j] = hb;
            l[j] = hw_f2bf(xs[j] - bf2f_raw((unsigned short)hb));
        }
        *reinterpret_cast<v8s*>(sBhi + g * 8) = h;
        *reinterpret_cast<v8s*>(sBlo + g * 8) = l;
    }
    __syncthreads();

    // ---- per-lane biases: u = (lane&15)*4+nb is in Ps half iff lane&15 < 8 ----
    v4f bias_vec = {0.f, 0.f, 0.f, 0.f};
    if ((lane & 15) < 8) {
        const float4 bv = *reinterpret_cast<const float4*>(b1 + (lane & 15) * 4);
        bias_vec[0] = bv.x; bias_vec[1] = bv.y;
        bias_vec[2] = bv.z; bias_vec[3] = bv.w;
    }

    // ---- Phase 1: 2 sub-tiles of 16 nodes per wave ----
    const int last = n_nodes - 1;
    const int grp  = lane >> 4;

#pragma unroll
    for (int sub = 0; sub < 2; ++sub) {
        const int node0 = blockIdx.x * 128 + wave * 32 + sub * 16;
        if (node0 >= n_nodes) break;
        const int row = min(node0 + (lane & 15), last);

        // A fragments: single bf16 rounding, plain coalesced loads (no NT)
        v8s ahi[4];
#pragma unroll
        for (int ks = 0; ks < 4; ++ks) {
            const float* ap = embed + (size_t)row * IN_FEATS + ks * 32 + grp * 8;
            const float4 x0 = *reinterpret_cast<const float4*>(ap);
            const float4 x1 = *reinterpret_cast<const float4*>(ap + 4);
            const float xs[8] = {x0.x, x0.y, x0.z, x0.w, x1.x, x1.y, x1.z, x1.w};
            v8s h;
#pragma unroll
            for (int j = 0; j < 8; ++j)
                h[j] = hw_f2bf(xs[j]);
            ahi[ks] = h;
        }

        // 4 nb-accumulators kept live for the packed store
        v4f acc[4];
#pragma unroll
        for (int nb = 0; nb < 4; ++nb) {
            v4f a = {0.f, 0.f, 0.f, 0.f};
#pragma unroll
            for (int ks = 0; ks < 4; ++ks) {
                const int fi = ((nb * 4 + ks) * 64 + lane) * 8;
                const v8s bhi = *reinterpret_cast<const v8s*>(sBhi + fi);
                const v8s blo = *reinterpret_cast<const v8s*>(sBlo + fi);
                a = __builtin_amdgcn_mfma_f32_16x16x32_bf16(ahi[ks], bhi, a, 0, 0, 0);
                a = __builtin_amdgcn_mfma_f32_16x16x32_bf16(ahi[ks], blo, a, 0, 0, 0);
            }
            acc[nb] = a;
        }

        // packed coalesced store: per r, one ushort4 (8B) per lane ->
        // 16 lanes x 8B = a full 128B row per 16-lane group.
#pragma unroll
        for (int r = 0; r < 4; ++r) {
            const int n = node0 + grp * 4 + r;
            if (n < n_nodes) {
                ushort4 v;
                v.x = (unsigned short)hw_f2bf(acc[0][r] + bias_vec[0]);
                v.y = (unsigned short)hw_f2bf(acc[1][r] + bias_vec[1]);
                v.z = (unsigned short)hw_f2bf(acc[2][r] + bias_vec[2]);
                v.w = (unsigned short)hw_f2bf(acc[3][r] + bias_vec[3]);
                *reinterpret_cast<ushort4*>(P + (size_t)n * 64 + (lane & 15) * 4) = v;
            }
        }
    }
}

// ---------------------------------------------------------------------------
// Kernel 2: per-edge  logits = relu(Ps[s] + Pd[d]) @ W2.T + b2   (b1 in Ps)
// 4 lanes per edge, 4 edges per quad (e+64k): 8 independent 16B gathers in
// flight per lane. One-shot grid, full TLP. Plain loads (R13: no NT).
// ---------------------------------------------------------------------------
__global__ __launch_bounds__(256) void edge_classify_bf16(
    const int* __restrict__ src,
    const int* __restrict__ dst,
    const unsigned short* __restrict__ P,   // bf16 [n][64]
    const float* __restrict__ W2,
    const float* __restrict__ b2,
    float* __restrict__ out,
    int n_edges)
{
    const int t   = threadIdx.x;
    const int q   = t & 3;                      // quad lane: units 8q..8q+7
    const int qid = t >> 2;                     // 0..63
    const int e0  = blockIdx.x * 256 + qid;
    if (e0 >= n_edges) return;

    int se[4], de[4];
#pragma unroll
    for (int k = 0; k < 4; ++k) {
        const int e  = e0 + k * 64;
        const int ec = (e < n_edges) ? e : e0;
        se[k] = src[ec];
        de[k] = dst[ec];
    }

    u16x8 ps[4], pd[4];
#pragma unroll
    for (int k = 0; k < 4; ++k) {
        ps[k] = *reinterpret_cast<const u16x8*>(P + (size_t)se[k] * 64 + q * 8);
        pd[k] = *reinterpret_cast<const u16x8*>(P + (size_t)de[k] * 64 + 32 + q * 8);
    }

    const float4 w0a = *reinterpret_cast<const float4*>(W2 + q * 8);
    const float4 w0b = *reinterpret_cast<const float4*>(W2 + q * 8 + 4);
    const float4 w1a = *reinterpret_cast<const float4*>(W2 + HIDDEN + q * 8);
    const float4 w1b = *reinterpret_cast<const float4*>(W2 + HIDDEN + q * 8 + 4);
    const float ww0[8] = {w0a.x, w0a.y, w0a.z, w0a.w, w0b.x, w0b.y, w0b.z, w0b.w};
    const float ww1[8] = {w1a.x, w1a.y, w1a.z, w1a.w, w1b.x, w1b.y, w1b.z, w1b.w};

    float l0[4] = {0.f, 0.f, 0.f, 0.f};
    float l1[4] = {0.f, 0.f, 0.f, 0.f};
#pragma unroll
    for (int k = 0; k < 4; ++k) {
#pragma unroll
        for (int j = 0; j < 8; ++j) {
            float h = bf2f_raw(ps[k][j]) + bf2f_raw(pd[k][j]);
            h = fmaxf(h, 0.f);
            l0[k] = fmaf(h, ww0[j], l0[k]);
            l1[k] = fmaf(h, ww1[j], l1[k]);
        }
    }
#pragma unroll
    for (int k = 0; k < 4; ++k) {
        l0[k] += __shfl_xor(l0[k], 1); l0[k] += __shfl_xor(l0[k], 2);
        l1[k] += __shfl_xor(l1[k], 1); l1[k] += __shfl_xor(l1[k], 2);
    }
    if (q == 0) {
        const float bias0 = b2[0], bias1 = b2[1];
#pragma unroll
        for (int k = 0; k < 4; ++k) {
            const int e = e0 + k * 64;
            if (e < n_edges)
                *reinterpret_cast<float2*>(out + (size_t)e * 2) =
                    make_float2(l0[k] + bias0, l1[k] + bias1);
        }
    }
}

// ---------------------------------------------------------------------------
// Fallback (only if workspace too small): direct per-edge computation.
// ---------------------------------------------------------------------------
__global__ __launch_bounds__(256) void edge_direct(
    const int* __restrict__ src, const int* __restrict__ dst,
    const float* __restrict__ embed,
    const float* __restrict__ W1, const float* __restrict__ b1,
    const float* __restrict__ W2, const float* __restrict__ b2,
    float* __restrict__ out, int n_edges)
{
    const int e = blockIdx.x * 256 + threadIdx.x;
    if (e >= n_edges) return;
    const int s = src[e], d = dst[e];
    const float* se = embed + (size_t)s * IN_FEATS;
    const float* de = embed + (size_t)d * IN_FEATS;

    float acc[HIDDEN];
#pragma unroll
    for (int hh = 0; hh < HIDDEN; ++hh) acc[hh] = b1[hh];

    for (int c = 0; c < 4; ++c) {
        float es[32], ed[32];
#pragma unroll
        for (int q = 0; q < 8; ++q) {
            const float4 v = *reinterpret_cast<const float4*>(se + c * 32 + q * 4);
            es[q*4+0] = v.x; es[q*4+1] = v.y; es[q*4+2] = v.z; es[q*4+3] = v.w;
            const float4 u = *reinterpret_cast<const float4*>(de + c * 32 + q * 4);
            ed[q*4+0] = u.x; ed[q*4+1] = u.y; ed[q*4+2] = u.z; ed[q*4+3] = u.w;
        }
#pragma unroll
        for (int hh = 0; hh < HIDDEN; ++hh) {
            float acch = acc[hh];
#pragma unroll
            for (int k = 0; k < 32; ++k) {
                acch = fmaf(es[k], W1[hh * 256 + c * 32 + k], acch);
                acch = fmaf(ed[k], W1[hh * 256 + 128 + c * 32 + k], acch);
            }
            acc[hh] = acch;
        }
    }

    float l0 = b2[0], l1 = b2[1];
#pragma unroll
    for (int hh = 0; hh < HIDDEN; ++hh) {
        const float hv = fmaxf(acc[hh], 0.f);
        l0 = fmaf(hv, W2[hh], l0);
        l1 = fmaf(hv, W2[HIDDEN + hh], l1);
    }
    *reinterpret_cast<float2*>(out + (size_t)e * 2) = make_float2(l0, l1);
}

extern "C" void kernel_launch(void* const* d_in, const int* in_sizes, int n_in,
                              void* d_out, int out_size, void* d_ws, size_t ws_size,
                              hipStream_t stream)
{
    const int*   src = (const int*)d_in[0];
    const int*   dst = (const int*)d_in[1];
    const float* emb = (const float*)d_in[2];
    const float* W1  = (const float*)d_in[3];
    const float* b1  = (const float*)d_in[4];
    const float* W2  = (const float*)d_in[5];
    const float* b2  = (const float*)d_in[6];
    float* out = (float*)d_out;

    const int n_edges = in_sizes[0];
    const int n_nodes = in_sizes[2] / IN_FEATS;

    const size_t p_bytes = (size_t)n_nodes * 64 * sizeof(unsigned short);

    if (ws_size >= p_bytes) {
        unsigned short* P = (unsigned short*)d_ws;
        const int nb_nodes = (n_nodes + 127) / 128;   // 128 nodes per block
        precompute_P_mfma<<<nb_nodes, 256, 0, stream>>>(emb, W1, b1, P, n_nodes);
        const int nb_edges = (n_edges + 255) / 256;   // 256 edges per block
        edge_classify_bf16<<<nb_edges, 256, 0, stream>>>(src, dst, P, W2, b2, out, n_edges);
    } else {
        const int nb_edges = (n_edges + 255) / 256;
        edge_direct<<<nb_edges, 256, 0, stream>>>(src, dst, emb, W1, b1, W2, b2, out, n_edges);
    }
}

// Round 15
// 38.896 us; speedup vs baseline: 1.2346x; 1.0154x over previous
//
#include <hip/hip_runtime.h>
#include <hip/hip_bf16.h>

#define IN_FEATS 128
#define HIDDEN 32

typedef short v8s __attribute__((ext_vector_type(8)));
typedef unsigned short u16x8 __attribute__((ext_vector_type(8)));
typedef float v4f __attribute__((ext_vector_type(4)));

__device__ __forceinline__ short hw_f2bf(float x) {
    __hip_bfloat16 b = __float2bfloat16(x);
    return *reinterpret_cast<short*>(&b);
}
__device__ __forceinline__ float bf2f_raw(unsigned short b) {
    union { float f; unsigned int u; } v; v.u = ((unsigned int)b) << 16;
    return v.f;
}

// ---------------------------------------------------------------------------
// Kernel 1: P[n][0:64] = embed[n] @ [W1s|W1d].T, b1 folded into the Ps half.
// R15: SINGLE pure-bf16 MFMA per K-step (dropped the Blo correction).
// Error budget: W bf16 rounding rel<=2^-9, |w|<=0.0625, K=128 ->
// logit-level addition ~0.004 worst case; predicted absmax ~0.012 << 0.029.
// Halves LDS traffic/footprint and MFMA count vs R14.
//
// u-mapping: u = (lane&15)*4 + nb -- after the nb loop each lane holds 4
// CONTIGUOUS units per output row; pack to ushort4, so each 16-lane group
// stores a full 128B row in one instruction.
// Fragment slot g=(nb*4+ks)*64+lane holds B[k][u], k=ks*32+((lane>>4)&3)*8+j;
// A uses the identical (group,j)->k map so any common k-permutation cancels.
// C/D (HW-verified): col = lane&15, row = (lane>>4)*4 + reg.
// R13 lesson: NO non-temporal hints.
// ---------------------------------------------------------------------------
__global__ __launch_bounds__(256, 4) void precompute_P_mfma(
    const float* __restrict__ embed,
    const float* __restrict__ W1,
    const float* __restrict__ b1,
    unsigned short* __restrict__ P,        // bf16 [n][64]
    int n_nodes)
{
    __shared__ unsigned short sB[8192];    // 16 KB (hi only)

    const int t    = threadIdx.x;
    const int lane = t & 63;
    const int wave = t >> 6;

    // ---- Phase 0: pack W fragments into LDS (once per block; W1 L2-hits) ----
#pragma unroll
    for (int g0 = 0; g0 < 1024; g0 += 256) {
        const int g   = g0 + t;
        const int gl  = g & 63;
        const int ks  = (g >> 6) & 3;
        const int nb  = g >> 8;
        const int u   = (gl & 15) * 4 + nb;
        const int k0  = ks * 32 + ((gl >> 4) & 3) * 8;
        const float* wp = W1 + (u & 31) * (2 * IN_FEATS) + (u >> 5) * IN_FEATS + k0;
        const float4 x0 = *reinterpret_cast<const float4*>(wp);
        const float4 x1 = *reinterpret_cast<const float4*>(wp + 4);
        const float xs[8] = {x0.x, x0.y, x0.z, x0.w, x1.x, x1.y, x1.z, x1.w};
        v8s h;
#pragma unroll
        for (int j = 0; j < 8; ++j)
            h[j] = hw_f2bf(xs[j]);
        *reinterpret_cast<v8s*>(sB + g * 8) = h;
    }
    __syncthreads();

    // ---- per-lane biases: u = (lane&15)*4+nb is in Ps half iff lane&15 < 8 ----
    v4f bias_vec = {0.f, 0.f, 0.f, 0.f};
    if ((lane & 15) < 8) {
        const float4 bv = *reinterpret_cast<const float4*>(b1 + (lane & 15) * 4);
        bias_vec[0] = bv.x; bias_vec[1] = bv.y;
        bias_vec[2] = bv.z; bias_vec[3] = bv.w;
    }

    // ---- Phase 1: 2 sub-tiles of 16 nodes per wave ----
    const int last = n_nodes - 1;
    const int grp  = lane >> 4;

#pragma unroll
    for (int sub = 0; sub < 2; ++sub) {
        const int node0 = blockIdx.x * 128 + wave * 32 + sub * 16;
        if (node0 >= n_nodes) break;
        const int row = min(node0 + (lane & 15), last);

        // A fragments: single bf16 rounding, plain coalesced loads
        v8s ahi[4];
#pragma unroll
        for (int ks = 0; ks < 4; ++ks) {
            const float* ap = embed + (size_t)row * IN_FEATS + ks * 32 + grp * 8;
            const float4 x0 = *reinterpret_cast<const float4*>(ap);
            const float4 x1 = *reinterpret_cast<const float4*>(ap + 4);
            const float xs[8] = {x0.x, x0.y, x0.z, x0.w, x1.x, x1.y, x1.z, x1.w};
            v8s h;
#pragma unroll
            for (int j = 0; j < 8; ++j)
                h[j] = hw_f2bf(xs[j]);
            ahi[ks] = h;
        }

        // 4 nb-accumulators kept live for the packed store
        v4f acc[4];
#pragma unroll
        for (int nb = 0; nb < 4; ++nb) {
            v4f a = {0.f, 0.f, 0.f, 0.f};
#pragma unroll
            for (int ks = 0; ks < 4; ++ks) {
                const int fi = ((nb * 4 + ks) * 64 + lane) * 8;
                const v8s bhi = *reinterpret_cast<const v8s*>(sB + fi);
                a = __builtin_amdgcn_mfma_f32_16x16x32_bf16(ahi[ks], bhi, a, 0, 0, 0);
            }
            acc[nb] = a;
        }

        // packed coalesced store: per r, one ushort4 (8B) per lane ->
        // 16 lanes x 8B = a full 128B row per 16-lane group.
#pragma unroll
        for (int r = 0; r < 4; ++r) {
            const int n = node0 + grp * 4 + r;
            if (n < n_nodes) {
                ushort4 v;
                v.x = (unsigned short)hw_f2bf(acc[0][r] + bias_vec[0]);
                v.y = (unsigned short)hw_f2bf(acc[1][r] + bias_vec[1]);
                v.z = (unsigned short)hw_f2bf(acc[2][r] + bias_vec[2]);
                v.w = (unsigned short)hw_f2bf(acc[3][r] + bias_vec[3]);
                *reinterpret_cast<ushort4*>(P + (size_t)n * 64 + (lane & 15) * 4) = v;
            }
        }
    }
}

// ---------------------------------------------------------------------------
// Kernel 2: per-edge  logits = relu(Ps[s] + Pd[d]) @ W2.T + b2   (b1 in Ps)
// 4 lanes per edge, 4 edges per quad (e+64k): 8 independent 16B gathers in
// flight per lane. One-shot grid, full TLP. Proven R14 structure, unchanged.
// ---------------------------------------------------------------------------
__global__ __launch_bounds__(256) void edge_classify_bf16(
    const int* __restrict__ src,
    const int* __restrict__ dst,
    const unsigned short* __restrict__ P,   // bf16 [n][64]
    const float* __restrict__ W2,
    const float* __restrict__ b2,
    float* __restrict__ out,
    int n_edges)
{
    const int t   = threadIdx.x;
    const int q   = t & 3;                      // quad lane: units 8q..8q+7
    const int qid = t >> 2;                     // 0..63
    const int e0  = blockIdx.x * 256 + qid;
    if (e0 >= n_edges) return;

    int se[4], de[4];
#pragma unroll
    for (int k = 0; k < 4; ++k) {
        const int e  = e0 + k * 64;
        const int ec = (e < n_edges) ? e : e0;
        se[k] = src[ec];
        de[k] = dst[ec];
    }

    u16x8 ps[4], pd[4];
#pragma unroll
    for (int k = 0; k < 4; ++k) {
        ps[k] = *reinterpret_cast<const u16x8*>(P + (size_t)se[k] * 64 + q * 8);
        pd[k] = *reinterpret_cast<const u16x8*>(P + (size_t)de[k] * 64 + 32 + q * 8);
    }

    const float4 w0a = *reinterpret_cast<const float4*>(W2 + q * 8);
    const float4 w0b = *reinterpret_cast<const float4*>(W2 + q * 8 + 4);
    const float4 w1a = *reinterpret_cast<const float4*>(W2 + HIDDEN + q * 8);
    const float4 w1b = *reinterpret_cast<const float4*>(W2 + HIDDEN + q * 8 + 4);
    const float ww0[8] = {w0a.x, w0a.y, w0a.z, w0a.w, w0b.x, w0b.y, w0b.z, w0b.w};
    const float ww1[8] = {w1a.x, w1a.y, w1a.z, w1a.w, w1b.x, w1b.y, w1b.z, w1b.w};

    float l0[4] = {0.f, 0.f, 0.f, 0.f};
    float l1[4] = {0.f, 0.f, 0.f, 0.f};
#pragma unroll
    for (int k = 0; k < 4; ++k) {
#pragma unroll
        for (int j = 0; j < 8; ++j) {
            float h = bf2f_raw(ps[k][j]) + bf2f_raw(pd[k][j]);
            h = fmaxf(h, 0.f);
            l0[k] = fmaf(h, ww0[j], l0[k]);
            l1[k] = fmaf(h, ww1[j], l1[k]);
        }
    }
#pragma unroll
    for (int k = 0; k < 4; ++k) {
        l0[k] += __shfl_xor(l0[k], 1); l0[k] += __shfl_xor(l0[k], 2);
        l1[k] += __shfl_xor(l1[k], 1); l1[k] += __shfl_xor(l1[k], 2);
    }
    if (q == 0) {
        const float bias0 = b2[0], bias1 = b2[1];
#pragma unroll
        for (int k = 0; k < 4; ++k) {
            const int e = e0 + k * 64;
            if (e < n_edges)
                *reinterpret_cast<float2*>(out + (size_t)e * 2) =
                    make_float2(l0[k] + bias0, l1[k] + bias1);
        }
    }
}

// ---------------------------------------------------------------------------
// Fallback (only if workspace too small): direct per-edge computation.
// ---------------------------------------------------------------------------
__global__ __launch_bounds__(256) void edge_direct(
    const int* __restrict__ src, const int* __restrict__ dst,
    const float* __restrict__ embed,
    const float* __restrict__ W1, const float* __restrict__ b1,
    const float* __restrict__ W2, const float* __restrict__ b2,
    float* __restrict__ out, int n_edges)
{
    const int e = blockIdx.x * 256 + threadIdx.x;
    if (e >= n_edges) return;
    const int s = src[e], d = dst[e];
    const float* se = embed + (size_t)s * IN_FEATS;
    const float* de = embed + (size_t)d * IN_FEATS;

    float acc[HIDDEN];
#pragma unroll
    for (int hh = 0; hh < HIDDEN; ++hh) acc[hh] = b1[hh];

    for (int c = 0; c < 4; ++c) {
        float es[32], ed[32];
#pragma unroll
        for (int q = 0; q < 8; ++q) {
            const float4 v = *reinterpret_cast<const float4*>(se + c * 32 + q * 4);
            es[q*4+0] = v.x; es[q*4+1] = v.y; es[q*4+2] = v.z; es[q*4+3] = v.w;
            const float4 u = *reinterpret_cast<const float4*>(de + c * 32 + q * 4);
            ed[q*4+0] = u.x; ed[q*4+1] = u.y; ed[q*4+2] = u.z; ed[q*4+3] = u.w;
        }
#pragma unroll
        for (int hh = 0; hh < HIDDEN; ++hh) {
            float acch = acc[hh];
#pragma unroll
            for (int k = 0; k < 32; ++k) {
                acch = fmaf(es[k], W1[hh * 256 + c * 32 + k], acch);
                acch = fmaf(ed[k], W1[hh * 256 + 128 + c * 32 + k], acch);
            }
            acc[hh] = acch;
        }
    }

    float l0 = b2[0], l1 = b2[1];
#pragma unroll
    for (int hh = 0; hh < HIDDEN; ++hh) {
        const float hv = fmaxf(acc[hh], 0.f);
        l0 = fmaf(hv, W2[hh], l0);
        l1 = fmaf(hv, W2[HIDDEN + hh], l1);
    }
    *reinterpret_cast<float2*>(out + (size_t)e * 2) = make_float2(l0, l1);
}

extern "C" void kernel_launch(void* const* d_in, const int* in_sizes, int n_in,
                              void* d_out, int out_size, void* d_ws, size_t ws_size,
                              hipStream_t stream)
{
    const int*   src = (const int*)d_in[0];
    const int*   dst = (const int*)d_in[1];
    const float* emb = (const float*)d_in[2];
    const float* W1  = (const float*)d_in[3];
    const float* b1  = (const float*)d_in[4];
    const float* W2  = (const float*)d_in[5];
    const float* b2  = (const float*)d_in[6];
    float* out = (float*)d_out;

    const int n_edges = in_sizes[0];
    const int n_nodes = in_sizes[2] / IN_FEATS;

    const size_t p_bytes = (size_t)n_nodes * 64 * sizeof(unsigned short);

    if (ws_size >= p_bytes) {
        unsigned short* P = (unsigned short*)d_ws;
        const int nb_nodes = (n_nodes + 127) / 128;   // 128 nodes per block
        precompute_P_mfma<<<nb_nodes, 256, 0, stream>>>(emb, W1, b1, P, n_nodes);
        const int nb_edges = (n_edges + 255) / 256;   // 256 edges per block
        edge_classify_bf16<<<nb_edges, 256, 0, stream>>>(src, dst, P, W2, b2, out, n_edges);
    } else {
        const int nb_edges = (n_edges + 255) / 256;
        edge_direct<<<nb_edges, 256, 0, stream>>>(src, dst, emb, W1, b1, W2, b2, out, n_edges);
    }
}